// Round 1
// baseline (94.675 us; speedup 1.0000x reference)
//
#include <hip/hip_runtime.h>
#include <math.h>

// Tropical min-max matmul: out[b,o] = min_i max(x[b,i], w[i,o])
// B=1024, I=512, O=512, fp32.
// Compute-bound on the vector ALU (no MFMA for min/max): floor ~6.8us.
// Tiling: BM=32 x BN=64 output tile, BK=32 K-slab, 256 threads, 2x4 acc/thread.
// Grid = (512/64, 1024/32) = (8,32) = 256 blocks -> 1 block/CU.

#define BM 32
#define BN 64
#define BK 32
#define TM 2
#define TN 4

__global__ __launch_bounds__(256) void minmax_kernel(
    const float* __restrict__ x,    // [B, I]
    const float* __restrict__ w,    // [I, O]
    float* __restrict__ out)        // [B, O]
{
    const int I = 512;
    const int O = 512;

    __shared__ float xs[BM][BK + 4];   // 32 x 36 floats (stride 144B, 16B-aligned)
    __shared__ float ws[BK][BN + 4];   // 32 x 68 floats (stride 272B, 16B-aligned)

    const int tid = threadIdx.x;
    const int tx  = tid & 15;          // o-direction, 16 threads
    const int ty  = tid >> 4;          // b-direction, 16 threads

    const int b0 = blockIdx.y * BM;
    const int o0 = blockIdx.x * BN;

    float acc[TM][TN];
#pragma unroll
    for (int m = 0; m < TM; ++m)
#pragma unroll
        for (int n = 0; n < TN; ++n)
            acc[m][n] = INFINITY;

    // x tile: BM*BK = 1024 floats = 256 float4 -> 1 per thread
    const int xr = tid >> 3;           // 0..31
    const int xc = (tid & 7) << 2;     // 0,4,...,28
    // w tile: BK*BN = 2048 floats = 512 float4 -> 2 per thread
    const int wr = tid >> 4;           // 0..15 (and +16)
    const int wc = (tid & 15) << 2;    // 0,4,...,60

    for (int k0 = 0; k0 < I; k0 += BK) {
        const float4 xv  = *(const float4*)(x + (size_t)(b0 + xr) * I + k0 + xc);
        const float4 wv0 = *(const float4*)(w + (size_t)(k0 + wr) * O + o0 + wc);
        const float4 wv1 = *(const float4*)(w + (size_t)(k0 + wr + 16) * O + o0 + wc);

        __syncthreads();   // protect previous iteration's LDS reads
        *(float4*)(&xs[xr][xc])      = xv;
        *(float4*)(&ws[wr][wc])      = wv0;
        *(float4*)(&ws[wr + 16][wc]) = wv1;
        __syncthreads();

#pragma unroll
        for (int k = 0; k < BK; ++k) {
            const float xv0 = xs[ty * TM + 0][k];
            const float xv1 = xs[ty * TM + 1][k];
            const float4 wv = *(const float4*)(&ws[k][tx * TN]);

            acc[0][0] = fminf(acc[0][0], fmaxf(xv0, wv.x));
            acc[0][1] = fminf(acc[0][1], fmaxf(xv0, wv.y));
            acc[0][2] = fminf(acc[0][2], fmaxf(xv0, wv.z));
            acc[0][3] = fminf(acc[0][3], fmaxf(xv0, wv.w));
            acc[1][0] = fminf(acc[1][0], fmaxf(xv1, wv.x));
            acc[1][1] = fminf(acc[1][1], fmaxf(xv1, wv.y));
            acc[1][2] = fminf(acc[1][2], fmaxf(xv1, wv.z));
            acc[1][3] = fminf(acc[1][3], fmaxf(xv1, wv.w));
        }
    }

#pragma unroll
    for (int m = 0; m < TM; ++m) {
        float4 r = make_float4(acc[m][0], acc[m][1], acc[m][2], acc[m][3]);
        *(float4*)(out + (size_t)(b0 + ty * TM + m) * O + o0 + tx * TN) = r;
    }
}

extern "C" void kernel_launch(void* const* d_in, const int* in_sizes, int n_in,
                              void* d_out, int out_size, void* d_ws, size_t ws_size,
                              hipStream_t stream) {
    const float* x = (const float*)d_in[0];   // [1024, 512]
    const float* w = (const float*)d_in[1];   // [512, 512]
    float* out = (float*)d_out;               // [1024, 512]

    dim3 grid(512 / BN, 1024 / BM);           // (8, 32) = 256 blocks
    dim3 block(256);
    minmax_kernel<<<grid, block, 0, stream>>>(x, w, out);
}

// Round 2
// 86.894 us; speedup vs baseline: 1.0895x; 1.0895x over previous
//
#include <hip/hip_runtime.h>
#include <math.h>

// Tropical min-max matmul: out[b,o] = min_i max(x[b,i], w[i,o])
// B=1024, I=512, O=512, fp32. VALU floor ~6.8us; LDS-pipe floor at this
// tiling (~0.5 float/elem) ~ (268M*4B*0.5)/61TBps ~ 8.7us.
//
// Round 2: 32x32 tile, 256 thr (4 waves), intra-block split-K: wave w owns
// k in [w*128, w*128+128), 4x4 reg tile/thread, cross-wave min via LDS.
// Grid 16x32 = 512 blocks = 2 blocks/CU = 8 waves/CU (2/SIMD).

#define BM 32
#define BN 32
#define KW 128        // k-range per wave
#define BK 32         // k per stage per wave
#define XS_STRIDE 36  // 32 + 4 pad (keeps b128 reads across 8 rows conflict-free)

__global__ __launch_bounds__(256, 2) void minmax_kernel(
    const float* __restrict__ x,    // [1024, 512]
    const float* __restrict__ w,    // [512, 512]
    float* __restrict__ out)        // [1024, 512]
{
    __shared__ float xs[4 * BM * XS_STRIDE];   // 18432 B (also reused as combine scratch)
    __shared__ float ws[4 * BK * BN];          // 16384 B

    const int t    = threadIdx.x;
    const int wv   = t >> 6;        // wave id 0..3 -> K-quarter
    const int lane = t & 63;
    const int nx   = lane & 7;      // o-group: cols nx*4..nx*4+3
    const int my   = lane >> 3;     // b-group: rows my, my+8, my+16, my+24

    const int b0 = blockIdx.y * BM;
    const int o0 = blockIdx.x * BN;

    // staging mapping (256 threads, 4 float4 each for x and w)
    const int lrow = t >> 3;        // 0..31
    const int lq   = (t & 7) * 4;   // 0,4,...,28

    float4 acc[4];
#pragma unroll
    for (int r = 0; r < 4; ++r)
        acc[r] = make_float4(INFINITY, INFINITY, INFINITY, INFINITY);

    // prefetch stage 0 (window j = wave j's k-chunk)
    float4 xg[4], wg[4];
#pragma unroll
    for (int j = 0; j < 4; ++j) {
        xg[j] = *(const float4*)(x + (size_t)(b0 + lrow) * 512 + j * KW + lq);
        wg[j] = *(const float4*)(w + (size_t)(j * KW + lrow) * 512 + o0 + lq);
    }

    const float* xw  = xs + wv * BM * XS_STRIDE;
    const float* wwp = ws + wv * BK * BN;

    for (int s = 0; s < 4; ++s) {
        __syncthreads();   // protect previous stage's LDS reads
#pragma unroll
        for (int j = 0; j < 4; ++j) {
            *(float4*)(xs + (j * BM + lrow) * XS_STRIDE + lq) = xg[j];
            *(float4*)(ws + (j * BK + lrow) * BN + lq)        = wg[j];
        }
        __syncthreads();

        if (s < 3) {   // prefetch next stage while computing this one
#pragma unroll
            for (int j = 0; j < 4; ++j) {
                xg[j] = *(const float4*)(x + (size_t)(b0 + lrow) * 512 + j * KW + (s + 1) * BK + lq);
                wg[j] = *(const float4*)(w + (size_t)(j * KW + (s + 1) * BK + lrow) * 512 + o0 + lq);
            }
        }

#pragma unroll
        for (int kk = 0; kk < BK; kk += 4) {
            float4 xf[4], wf[4];
#pragma unroll
            for (int r = 0; r < 4; ++r)
                xf[r] = *(const float4*)(xw + (my + 8 * r) * XS_STRIDE + kk);
#pragma unroll
            for (int j = 0; j < 4; ++j)
                wf[j] = *(const float4*)(wwp + (kk + j) * BN + nx * 4);
#pragma unroll
            for (int j = 0; j < 4; ++j) {
#pragma unroll
                for (int r = 0; r < 4; ++r) {
                    const float xv = ((const float*)&xf[r])[j];
                    acc[r].x = fminf(acc[r].x, fmaxf(xv, wf[j].x));
                    acc[r].y = fminf(acc[r].y, fmaxf(xv, wf[j].y));
                    acc[r].z = fminf(acc[r].z, fmaxf(xv, wf[j].z));
                    acc[r].w = fminf(acc[r].w, fmaxf(xv, wf[j].w));
                }
            }
        }
    }

    // cross-wave min combine: reuse xs as scratch (need 4096 floats, have 4608)
    __syncthreads();   // all waves done reading tiles
    float* scr = xs;
#pragma unroll
    for (int r = 0; r < 4; ++r)
        *(float4*)(scr + wv * 1024 + (my + 8 * r) * 32 + nx * 4) = acc[r];
    __syncthreads();

    const int orow = t >> 3;          // 0..31
    const int ocol = (t & 7) * 4;     // 0,4,...,28
    const float4 v0 = *(const float4*)(scr + 0 * 1024 + t * 4);
    const float4 v1 = *(const float4*)(scr + 1 * 1024 + t * 4);
    const float4 v2 = *(const float4*)(scr + 2 * 1024 + t * 4);
    const float4 v3 = *(const float4*)(scr + 3 * 1024 + t * 4);
    float4 rr;
    rr.x = fminf(fminf(v0.x, v1.x), fminf(v2.x, v3.x));
    rr.y = fminf(fminf(v0.y, v1.y), fminf(v2.y, v3.y));
    rr.z = fminf(fminf(v0.z, v1.z), fminf(v2.z, v3.z));
    rr.w = fminf(fminf(v0.w, v1.w), fminf(v2.w, v3.w));
    *(float4*)(out + (size_t)(b0 + orow) * 512 + o0 + ocol) = rr;
}

extern "C" void kernel_launch(void* const* d_in, const int* in_sizes, int n_in,
                              void* d_out, int out_size, void* d_ws, size_t ws_size,
                              hipStream_t stream) {
    const float* x = (const float*)d_in[0];   // [1024, 512]
    const float* w = (const float*)d_in[1];   // [512, 512]
    float* out = (float*)d_out;               // [1024, 512]

    dim3 grid(512 / BN, 1024 / BM);           // (16, 32) = 512 blocks
    dim3 block(256);
    minmax_kernel<<<grid, block, 0, stream>>>(x, w, out);
}

// Round 3
// 84.458 us; speedup vs baseline: 1.1210x; 1.0288x over previous
//
#include <hip/hip_runtime.h>
#include <math.h>

// Tropical min-max matmul: out[b,o] = min_i max(x[b,i], w[i,o])
// B=1024, I=512, O=512, fp32.
//
// Round 3 design:
//  - 128x128 block tile, 256 threads, 8x8 outputs/thread (64 acc VGPRs).
//  - Cross-block split-K = 8 (K=64/block, 2 slabs of BK=32) -> grid 4x8x8
//    = 256 blocks = 1 block/CU (4 waves, 1/SIMD). Partials in d_ws,
//    combined by a second elementwise-min kernel (no device atomics).
//  - VALU: acc = min3(acc, max(x0,w0), max(x1,w1)) -> 1.5 inst/update,
//    floor ~5.1us. LDS: 16 ds_read_b128 per 4k per wave -> ~5.1us. Balanced.
//  - LDS layouts (no transposes, all compute reads b128, conflict-free):
//      xs[row][k]  stride 36 (144B, 16B-aligned): rows ty+16r -> quads
//                  (ty+k4) mod 8 distinct, 16-lane broadcast groups.
//      ws[k][col]  stride 128: cols tx*4(+64g) -> 8 quads x 2-way (free).

#define BKS 32
#define XS_STRIDE 36

__device__ __forceinline__ float4 vmax(float s, float4 v) {
    return make_float4(fmaxf(s, v.x), fmaxf(s, v.y), fmaxf(s, v.z), fmaxf(s, v.w));
}
__device__ __forceinline__ float4 vmin3(float4 a, float4 b, float4 c) {
    // fmin(fmin(a,b),c) -> v_min3_f32
    return make_float4(fminf(fminf(a.x, b.x), c.x),
                       fminf(fminf(a.y, b.y), c.y),
                       fminf(fminf(a.z, b.z), c.z),
                       fminf(fminf(a.w, b.w), c.w));
}

__global__ __launch_bounds__(256) void minmax_part(
    const float* __restrict__ x,    // [1024, 512]
    const float* __restrict__ w,    // [512, 512]
    float* __restrict__ dst,        // partials (or out when gridDim.z==1)
    int nslab)                      // k-slabs of 32 per block
{
    __shared__ float xs[128 * XS_STRIDE];   // 18432 B
    __shared__ float ws[BKS * 128];         // 16384 B

    const int t  = threadIdx.x;
    const int tx = t & 15;          // col group: cols tx*4..+3 and 64+tx*4..+3
    const int ty = t >> 4;          // row group: rows ty+16r, r=0..7

    const int o0 = blockIdx.x * 128;
    const int b0 = blockIdx.y * 128;
    const int kbase = blockIdx.z * nslab * BKS;

    float4 acc[8][2];
#pragma unroll
    for (int r = 0; r < 8; ++r)
#pragma unroll
        for (int g = 0; g < 2; ++g)
            acc[r][g] = make_float4(INFINITY, INFINITY, INFINITY, INFINITY);

    for (int s = 0; s < nslab; ++s) {
        const int kb = kbase + s * BKS;

        __syncthreads();   // protect previous slab's LDS reads
        // stage x tile [128 rows][32 k], coalesced, b128 LDS writes
#pragma unroll
        for (int i = 0; i < 4; ++i) {
            const int f = i * 256 + t;
            const int row = f >> 3, c4 = f & 7;
            const float4 v = *(const float4*)(x + (size_t)(b0 + row) * 512 + kb + 4 * c4);
            *(float4*)(xs + row * XS_STRIDE + 4 * c4) = v;
        }
        // stage w tile [32 k][128 cols], coalesced, b128 LDS writes
#pragma unroll
        for (int i = 0; i < 4; ++i) {
            const int f = i * 256 + t;
            const int k = f >> 5, c4 = f & 31;
            const float4 v = *(const float4*)(w + (size_t)(kb + k) * 512 + o0 + 4 * c4);
            *(float4*)(ws + k * 128 + 4 * c4) = v;
        }
        __syncthreads();

#pragma unroll 2
        for (int k4 = 0; k4 < BKS / 4; ++k4) {
            float4 xf[8];
#pragma unroll
            for (int r = 0; r < 8; ++r)
                xf[r] = *(const float4*)(xs + (ty + 16 * r) * XS_STRIDE + 4 * k4);
            float4 wf[4][2];
#pragma unroll
            for (int j = 0; j < 4; ++j)
#pragma unroll
                for (int g = 0; g < 2; ++g)
                    wf[j][g] = *(const float4*)(ws + (4 * k4 + j) * 128 + tx * 4 + 64 * g);
#pragma unroll
            for (int r = 0; r < 8; ++r) {
#pragma unroll
                for (int g = 0; g < 2; ++g) {
                    float4 a = acc[r][g];
                    a = vmin3(a, vmax(xf[r].x, wf[0][g]), vmax(xf[r].y, wf[1][g]));
                    a = vmin3(a, vmax(xf[r].z, wf[2][g]), vmax(xf[r].w, wf[3][g]));
                    acc[r][g] = a;
                }
            }
        }
    }

    // epilogue: coalesced float4 stores (cols tx*4 are 4-contiguous)
    float* outp = dst + (size_t)blockIdx.z * (1024 * 512);
#pragma unroll
    for (int r = 0; r < 8; ++r)
#pragma unroll
        for (int g = 0; g < 2; ++g)
            *(float4*)(outp + (size_t)(b0 + ty + 16 * r) * 512 + o0 + tx * 4 + 64 * g) = acc[r][g];
}

__global__ __launch_bounds__(256) void minmax_reduce(
    const float* __restrict__ part, float* __restrict__ out)
{
    const int i = blockIdx.x * 256 + threadIdx.x;   // float4 index, 131072 total
    const float4* p = (const float4*)part;
    float4 v = p[i];
#pragma unroll
    for (int s = 1; s < 8; ++s) {
        const float4 u = p[i + s * 131072];
        v.x = fminf(v.x, u.x);
        v.y = fminf(v.y, u.y);
        v.z = fminf(v.z, u.z);
        v.w = fminf(v.w, u.w);
    }
    ((float4*)out)[i] = v;
}

extern "C" void kernel_launch(void* const* d_in, const int* in_sizes, int n_in,
                              void* d_out, int out_size, void* d_ws, size_t ws_size,
                              hipStream_t stream) {
    const float* x = (const float*)d_in[0];   // [1024, 512]
    const float* w = (const float*)d_in[1];   // [512, 512]
    float* out = (float*)d_out;               // [1024, 512]

    const size_t need = 8ull * 1024 * 512 * 4;   // 16 MB of partials
    if (ws_size >= need) {
        minmax_part<<<dim3(4, 8, 8), 256, 0, stream>>>(x, w, (float*)d_ws, 2);
        minmax_reduce<<<dim3(512), 256, 0, stream>>>((const float*)d_ws, out);
    } else {
        // fallback: no split-K, 32 blocks, write out directly (correct, slower)
        minmax_part<<<dim3(4, 8, 1), 256, 0, stream>>>(x, w, out, 16);
    }
}

// Round 4
// 83.985 us; speedup vs baseline: 1.1273x; 1.0056x over previous
//
#include <hip/hip_runtime.h>
#include <math.h>

// Tropical min-max matmul: out[b,o] = min_i max(x[b,i], w[i,o])
// B=1024, I=512, O=512, fp32.
//
// Round 4:
//  - 64x128 block tile, 256 threads (4 waves), 4x8 outputs/thread (32 acc).
//  - split-K = 8 (K=64/block, 2 slabs of 32) -> grid 4x16x8 = 512 blocks
//    = 2 blocks/CU = 8 waves/CU = 2 waves/SIMD (latency hiding + dispatch
//    balance; round-3's 256-block/1-wave-per-SIMD config was latency-bound).
//  - acc = min3(acc, max(x0,w0), max(x1,w1)) -> 1.5 VALU inst/update,
//    VALU floor ~5.1us/SIMD; LDS: wf 8 b128/thread/k4 (full-BW) + xf 4
//    (16-lane broadcast, cheap) ~ 5.8us. Balanced, now with TLP.
//  - xs stride 36: xf rows ty+16r -> 4 distinct quads/wave, conflict-free
//    broadcast. ws stride 128: wf cols tx*4+64g -> 2-way aliasing (free).

#define XS_STRIDE 36

__device__ __forceinline__ float4 vmax4(float s, float4 v) {
    return make_float4(fmaxf(s, v.x), fmaxf(s, v.y), fmaxf(s, v.z), fmaxf(s, v.w));
}
__device__ __forceinline__ float4 vmin3(float4 a, float4 b, float4 c) {
    // fmin(fmin(a,b),c) -> v_min3_f32
    return make_float4(fminf(fminf(a.x, b.x), c.x),
                       fminf(fminf(a.y, b.y), c.y),
                       fminf(fminf(a.z, b.z), c.z),
                       fminf(fminf(a.w, b.w), c.w));
}

__global__ __launch_bounds__(256, 2) void minmax_part(
    const float* __restrict__ x,    // [1024, 512]
    const float* __restrict__ w,    // [512, 512]
    float* __restrict__ dst,        // partial slices (or out when gridDim.z==1)
    int nslab)                      // k-slabs of 32 per block
{
    __shared__ float xs[64 * XS_STRIDE];   //  9216 B
    __shared__ float ws[32 * 128];         // 16384 B

    const int t  = threadIdx.x;
    const int tx = t & 15;          // col group: cols tx*4..+3 and 64+tx*4..+3
    const int ty = t >> 4;          // row group: rows ty+16r, r=0..3

    const int o0 = blockIdx.x * 128;
    const int b0 = blockIdx.y * 64;
    const int kbase = blockIdx.z * nslab * 32;

    // staging maps
    const int xrow = t >> 3;        // 0..31 (x: 2 float4/thread, rows 0..63)
    const int xc4  = (t & 7) * 4;
    const int wk   = t >> 5;        // 0..7  (w: 4 float4/thread, k 0..31)
    const int wc4  = (t & 31) * 4;

    float4 acc[4][2];
#pragma unroll
    for (int r = 0; r < 4; ++r)
#pragma unroll
        for (int g = 0; g < 2; ++g)
            acc[r][g] = make_float4(INFINITY, INFINITY, INFINITY, INFINITY);

    // prefetch slab 0 into registers
    float4 xg[2], wg[4];
#pragma unroll
    for (int i = 0; i < 2; ++i)
        xg[i] = *(const float4*)(x + (size_t)(b0 + xrow + 32 * i) * 512 + kbase + xc4);
#pragma unroll
    for (int i = 0; i < 4; ++i)
        wg[i] = *(const float4*)(w + (size_t)(kbase + wk + 8 * i) * 512 + o0 + wc4);

    for (int s = 0; s < nslab; ++s) {
        __syncthreads();   // protect previous slab's LDS reads
#pragma unroll
        for (int i = 0; i < 2; ++i)
            *(float4*)(xs + (xrow + 32 * i) * XS_STRIDE + xc4) = xg[i];
#pragma unroll
        for (int i = 0; i < 4; ++i)
            *(float4*)(ws + (wk + 8 * i) * 128 + wc4) = wg[i];
        __syncthreads();

        if (s + 1 < nslab) {   // prefetch next slab while computing this one
            const int kb = kbase + (s + 1) * 32;
#pragma unroll
            for (int i = 0; i < 2; ++i)
                xg[i] = *(const float4*)(x + (size_t)(b0 + xrow + 32 * i) * 512 + kb + xc4);
#pragma unroll
            for (int i = 0; i < 4; ++i)
                wg[i] = *(const float4*)(w + (size_t)(kb + wk + 8 * i) * 512 + o0 + wc4);
        }

#pragma unroll
        for (int k4 = 0; k4 < 8; ++k4) {
            float4 xf[4];
#pragma unroll
            for (int r = 0; r < 4; ++r)
                xf[r] = *(const float4*)(xs + (ty + 16 * r) * XS_STRIDE + 4 * k4);
            float4 wf[4][2];
#pragma unroll
            for (int j = 0; j < 4; ++j)
#pragma unroll
                for (int g = 0; g < 2; ++g)
                    wf[j][g] = *(const float4*)(ws + (4 * k4 + j) * 128 + tx * 4 + 64 * g);
#pragma unroll
            for (int r = 0; r < 4; ++r) {
#pragma unroll
                for (int g = 0; g < 2; ++g) {
                    float4 a = acc[r][g];
                    a = vmin3(a, vmax4(xf[r].x, wf[0][g]), vmax4(xf[r].y, wf[1][g]));
                    a = vmin3(a, vmax4(xf[r].z, wf[2][g]), vmax4(xf[r].w, wf[3][g]));
                    acc[r][g] = a;
                }
            }
        }
    }

    // epilogue: coalesced float4 stores
    float* outp = dst + (size_t)blockIdx.z * (1024 * 512);
#pragma unroll
    for (int r = 0; r < 4; ++r)
#pragma unroll
        for (int g = 0; g < 2; ++g)
            *(float4*)(outp + (size_t)(b0 + ty + 16 * r) * 512 + o0 + tx * 4 + 64 * g) = acc[r][g];
}

__global__ __launch_bounds__(256) void minmax_reduce(
    const float* __restrict__ part, float* __restrict__ out)
{
    const int i = blockIdx.x * 256 + threadIdx.x;   // float4 index, 131072 total
    const float4* p = (const float4*)part;
    float4 v = p[i];
#pragma unroll
    for (int s = 1; s < 8; ++s) {
        const float4 u = p[i + s * 131072];
        v.x = fminf(v.x, u.x);
        v.y = fminf(v.y, u.y);
        v.z = fminf(v.z, u.z);
        v.w = fminf(v.w, u.w);
    }
    ((float4*)out)[i] = v;
}

extern "C" void kernel_launch(void* const* d_in, const int* in_sizes, int n_in,
                              void* d_out, int out_size, void* d_ws, size_t ws_size,
                              hipStream_t stream) {
    const float* x = (const float*)d_in[0];   // [1024, 512]
    const float* w = (const float*)d_in[1];   // [512, 512]
    float* out = (float*)d_out;               // [1024, 512]

    const size_t need = 8ull * 1024 * 512 * 4;   // 16 MB of partials
    if (ws_size >= need) {
        minmax_part<<<dim3(4, 16, 8), 256, 0, stream>>>(x, w, (float*)d_ws, 2);
        minmax_reduce<<<dim3(512), 256, 0, stream>>>((const float*)d_ws, out);
    } else {
        // fallback: no split-K, write out directly (correct, slower)
        minmax_part<<<dim3(4, 16, 1), 256, 0, stream>>>(x, w, out, 16);
    }
}